// Round 5
// baseline (270.505 us; speedup 1.0000x reference)
//
#include <hip/hip_runtime.h>

// PennSkipGramModel forward: mean over B of
//   -logsig(clip(u_l·v_l)) + -logsig(clip(u_r·v_r))
//   + sum_k -logsig(-clip(u_l·neg_l[k])) + sum_k -logsig(-clip(u_r·neg_r[k]))
//
// R4 lesson: butterfly reduce-scatter serialized on the DS pipe + cndmask
// overhead (VALUBusy 92%, 116us). Reverted.
// R3 lesson: compiler sank the "prefetch" (VGPR=20 < 28-reg payload) —
// sched_barrier alone does not hold a prefetch across regalloc pressure.
//
// This version — forced MLP + DPP reduction:
//  * 32 lanes per element, one float4/lane = one whole 512B row per load.
//  * ALL 14 row loads are volatile inline-asm global_load_dwordx4 with
//    "=v" outputs: the compiler CANNOT sink, split, or spill them.
//    14 outstanding loads/wave guaranteed at machine level.
//  * One s_waitcnt vmcnt(0) + sched_barrier(0) before first use (rule #18).
//  * Reductions via DPP (row_shr 1/2/4/8 + row_bcast15): VALU-only, DS pipe
//    untouched, 12 independent 5-add chains -> full ILP.
//  * Payload 56 VGPR -> ~80 total -> 6 waves/SIMD; ~330 outstanding/CU.

#define BATCH 65536
#define K     5

__device__ __forceinline__ float clip10(float x) {
    return fminf(fmaxf(x, -10.0f), 10.0f);
}

__device__ __forceinline__ float dot4(float4 a, float4 b) {
    return a.x * b.x + a.y * b.y + a.z * b.z + a.w * b.w;
}

// x += dpp_move(x); CTRL: 0x111=row_shr:1 0x112=shr:2 0x114=shr:4
// 0x118=shr:8 0x142=row_bcast15. Disabled rows (RMASK) add old=0 (no-op).
template<int CTRL, int RMASK = 0xf>
__device__ __forceinline__ float dpp_add(float x) {
    int y = __builtin_amdgcn_update_dpp(0, __float_as_int(x), CTRL, RMASK, 0xf, true);
    return x + __int_as_float(y);
}

// 32-lane sum; result valid in lane 31 of each 32-lane half (lanes 31, 63).
__device__ __forceinline__ float wsum32(float x) {
    x = dpp_add<0x111>(x);        // + lane-1   (within 16-row)
    x = dpp_add<0x112>(x);        // + lane-2
    x = dpp_add<0x114>(x);        // + lane-4
    x = dpp_add<0x118>(x);        // + lane-8 -> lane15/31/47/63 = 16-row sums
    x = dpp_add<0x142, 0xa>(x);   // bcast15 into rows 1,3 -> lanes 31,63 = 32-sum
    return x;
}

#define LOAD_ROW(dst, base, idx)                                              \
    {                                                                         \
        const float4* _p = (const float4*)(base) + (((size_t)(idx)) << 5) + lig; \
        asm volatile("global_load_dwordx4 %0, %1, off" : "=v"(dst) : "v"(_p)); \
    }

__global__ __launch_bounds__(256) void skipgram_fwd(
    const float* __restrict__ u_l, const float* __restrict__ u_r,
    const float* __restrict__ v_l, const float* __restrict__ v_r,
    const int* __restrict__ pos_u, const int* __restrict__ pos_vl,
    const int* __restrict__ pos_vr, const int* __restrict__ neg_vl,
    const int* __restrict__ neg_vr, float* __restrict__ out)
{
    const int tid = threadIdx.x;
    const int lig = tid & 31;            // lane within 32-lane group
    const int e   = tid >> 5;            // element slot in block, 0..7
    const int b   = (blockIdx.x << 3) + e;

    // ---- indices (uniform within each 32-lane group) ----
    const int iu  = pos_u[b];
    const int ivl = pos_vl[b];
    const int ivr = pos_vr[b];
    const int in0 = neg_vl[b * K + 0], in1 = neg_vl[b * K + 1],
              in2 = neg_vl[b * K + 2], in3 = neg_vl[b * K + 3],
              in4 = neg_vl[b * K + 4];
    const int ir0 = neg_vr[b * K + 0], ir1 = neg_vr[b * K + 1],
              ir2 = neg_vr[b * K + 2], ir3 = neg_vr[b * K + 3],
              ir4 = neg_vr[b * K + 4];

    // ---- 14 forced-in-flight row loads (512B each, fully coalesced) ----
    float4 rul, rur, rvl, rvr;
    float4 nl0, nl1, nl2, nl3, nl4;
    float4 nr0, nr1, nr2, nr3, nr4;
    LOAD_ROW(rul, u_l, iu);
    LOAD_ROW(rur, u_r, iu);
    LOAD_ROW(rvl, v_l, ivl);
    LOAD_ROW(rvr, v_r, ivr);
    LOAD_ROW(nl0, v_l, in0);
    LOAD_ROW(nl1, v_l, in1);
    LOAD_ROW(nl2, v_l, in2);
    LOAD_ROW(nl3, v_l, in3);
    LOAD_ROW(nl4, v_l, in4);
    LOAD_ROW(nr0, v_r, ir0);
    LOAD_ROW(nr1, v_r, ir1);
    LOAD_ROW(nr2, v_r, ir2);
    LOAD_ROW(nr3, v_r, ir3);
    LOAD_ROW(nr4, v_r, ir4);

    asm volatile("s_waitcnt vmcnt(0)" ::: "memory");
    __builtin_amdgcn_sched_barrier(0);   // nothing crosses the waitcnt

    // ---- per-lane partial dots (12 independent values) ----
    float p[12];
    p[0]  = dot4(rul, rvl);
    p[1]  = dot4(rur, rvr);
    p[2]  = dot4(rul, nl0);
    p[3]  = dot4(rul, nl1);
    p[4]  = dot4(rul, nl2);
    p[5]  = dot4(rul, nl3);
    p[6]  = dot4(rul, nl4);
    p[7]  = dot4(rur, nr0);
    p[8]  = dot4(rur, nr1);
    p[9]  = dot4(rur, nr2);
    p[10] = dot4(rur, nr3);
    p[11] = dot4(rur, nr4);

    // ---- DPP reductions + logsig; acc valid in lanes 31/63 ----
    float acc = 0.0f;
    #pragma unroll
    for (int i = 0; i < 12; ++i) {
        float s = clip10(wsum32(p[i]));
        // i<2: -logsig(s) = log(1+exp(-s)); else: -logsig(-s) = log(1+exp(s))
        float x = (i < 2) ? -s : s;
        acc += __logf(1.0f + __expf(x));
    }

    // ---- block reduction: 8 elements -> 1 atomic ----
    __shared__ float smem[8];
    if (lig == 31) smem[e] = acc;
    __syncthreads();
    if (tid == 0) {
        float s = 0.0f;
        #pragma unroll
        for (int i = 0; i < 8; ++i) s += smem[i];
        atomicAdd(out, s * (1.0f / BATCH));
    }
}

extern "C" void kernel_launch(void* const* d_in, const int* in_sizes, int n_in,
                              void* d_out, int out_size, void* d_ws, size_t ws_size,
                              hipStream_t stream) {
    const float* u_l   = (const float*)d_in[0];
    const float* u_r   = (const float*)d_in[1];
    const float* v_l   = (const float*)d_in[2];
    const float* v_r   = (const float*)d_in[3];
    const int* pos_u   = (const int*)d_in[4];
    const int* pos_vl  = (const int*)d_in[5];
    const int* pos_vr  = (const int*)d_in[6];
    const int* neg_vl  = (const int*)d_in[7];
    const int* neg_vr  = (const int*)d_in[8];
    float* out = (float*)d_out;

    // d_out is poisoned (0xAA) before every timed launch — zero it on-stream.
    hipMemsetAsync(out, 0, sizeof(float), stream);

    skipgram_fwd<<<BATCH / 8, 256, 0, stream>>>(
        u_l, u_r, v_l, v_r, pos_u, pos_vl, pos_vr, neg_vl, neg_vr, out);
}

// Round 6
// 229.598 us; speedup vs baseline: 1.1782x; 1.1782x over previous
//
#include <hip/hip_runtime.h>

// PennSkipGramModel forward: mean over B of
//   -logsig(clip(u_l·v_l)) + -logsig(clip(u_r·v_r))
//   + sum_k -logsig(-clip(u_l·neg_l[k])) + sum_k -logsig(-clip(u_r·neg_r[k]))
//
// FINAL (revert to R3, the measured equal-best):
//   64 lanes (one wave) per batch element, float2 per lane per row.
//   - one global_load_dwordx2 = one whole 512B row, perfectly contiguous
//   - wave-uniform b (readfirstlane) -> scalar index loads, SGPR row bases
//   - compiler-scheduled partial vmcnt waits (measured optimal vs both
//     vmcnt(0) hard-batching [R5: -45%] and register-pinned prefetch
//     [R2: spills, -80%])
//
// Why stop here (counter evidence, rounds 0-5):
//   * FETCH_SIZE pinned at 226MB across all structures (~1.48x the
//     global-unique-row floor of 153MB — L2s already cache near-optimally;
//     indices are uniform-random, unsortable, bipartite).
//   * Read-miss stream 226MB/86us = 2.63 TB/s; request delivery plateaus at
//     miss_BW/miss_ratio = 5.5 TB/s in three independent structures.
//   * MLP sweep 50->280 outstanding/CU: flat then NEGATIVE. CU-side pipes
//     all idle (VALUBusy<=43%, occ 34-81%, 0 conflicts, 0 spills).
//   => bound by the random-512B L2-miss path (~2.7 TB/s); floor ~84us.

#define BATCH 65536
#define K     5

__device__ __forceinline__ float red64(float v) {
    v += __shfl_xor(v, 32);
    v += __shfl_xor(v, 16);
    v += __shfl_xor(v, 8);
    v += __shfl_xor(v, 4);
    v += __shfl_xor(v, 2);
    v += __shfl_xor(v, 1);
    return v;   // full sum in all 64 lanes
}

__device__ __forceinline__ float clip10(float x) {
    return fminf(fmaxf(x, -10.0f), 10.0f);
}

__device__ __forceinline__ float dot2(float2 a, float2 b) {
    return a.x * b.x + a.y * b.y;
}

__global__ __launch_bounds__(1024) void skipgram_fwd(
    const float* __restrict__ u_l, const float* __restrict__ u_r,
    const float* __restrict__ v_l, const float* __restrict__ v_r,
    const int* __restrict__ pos_u, const int* __restrict__ pos_vl,
    const int* __restrict__ pos_vr, const int* __restrict__ neg_vl,
    const int* __restrict__ neg_vr, float* __restrict__ out)
{
    const int tid  = threadIdx.x;
    const int lane = tid & 63;
    // wave id within block; readfirstlane makes it provably wave-uniform so
    // index loads scalarize (s_load) and row bases land in SGPRs.
    const int wid  = __builtin_amdgcn_readfirstlane(tid >> 6);   // 0..15
    const int b    = (blockIdx.x << 4) + wid;

    // ---- phase 0: 13 wave-uniform index loads (scalar) ----
    const int iu  = pos_u[b];
    const int ivl = pos_vl[b];
    const int ivr = pos_vr[b];
    int inl[K], inr[K];
    #pragma unroll
    for (int k = 0; k < K; ++k) {
        inl[k] = neg_vl[b * K + k];
        inr[k] = neg_vr[b * K + k];
    }

    // ---- phase 1: all 14 row loads (float2/lane = 512B/row/instr) ----
    const float2* ULr = (const float2*)u_l + ((size_t)iu  << 6);
    const float2* URr = (const float2*)u_r + ((size_t)iu  << 6);
    const float2* VLr = (const float2*)v_l + ((size_t)ivl << 6);
    const float2* VRr = (const float2*)v_r + ((size_t)ivr << 6);

    float2 ul = ULr[lane];
    float2 ur = URr[lane];
    float2 vl = VLr[lane];
    float2 vr = VRr[lane];

    float2 nl[K], nr[K];
    #pragma unroll
    for (int k = 0; k < K; ++k) {
        nl[k] = ((const float2*)v_l + ((size_t)inl[k] << 6))[lane];
        nr[k] = ((const float2*)v_r + ((size_t)inr[k] << 6))[lane];
    }

    __builtin_amdgcn_sched_barrier(0);

    // ---- phase 2: compute ----
    float sl = red64(dot2(ul, vl));
    float sr = red64(dot2(ur, vr));

    // -log_sigmoid(x) = log(1 + exp(-x)),  x clipped to [-10,10]
    float acc = __logf(1.0f + __expf(-clip10(sl)))
              + __logf(1.0f + __expf(-clip10(sr)));

    #pragma unroll
    for (int k = 0; k < K; ++k) {
        float snl = red64(dot2(ul, nl[k]));
        float snr = red64(dot2(ur, nr[k]));
        // -log_sigmoid(-x) = log(1 + exp(x))
        acc += __logf(1.0f + __expf(clip10(snl)))
             + __logf(1.0f + __expf(clip10(snr)));
    }

    // ---- block reduction: 16 waves -> 1 atomic per block ----
    __shared__ float smem[16];
    if (lane == 0) smem[wid] = acc;
    __syncthreads();
    if (tid == 0) {
        float s = 0.0f;
        #pragma unroll
        for (int i = 0; i < 16; ++i) s += smem[i];
        atomicAdd(out, s * (1.0f / BATCH));
    }
}

extern "C" void kernel_launch(void* const* d_in, const int* in_sizes, int n_in,
                              void* d_out, int out_size, void* d_ws, size_t ws_size,
                              hipStream_t stream) {
    const float* u_l   = (const float*)d_in[0];
    const float* u_r   = (const float*)d_in[1];
    const float* v_l   = (const float*)d_in[2];
    const float* v_r   = (const float*)d_in[3];
    const int* pos_u   = (const int*)d_in[4];
    const int* pos_vl  = (const int*)d_in[5];
    const int* pos_vr  = (const int*)d_in[6];
    const int* neg_vl  = (const int*)d_in[7];
    const int* neg_vr  = (const int*)d_in[8];
    float* out = (float*)d_out;

    // d_out is poisoned (0xAA) before every timed launch — zero it on-stream.
    hipMemsetAsync(out, 0, sizeof(float), stream);

    skipgram_fwd<<<BATCH / 16, 1024, 0, stream>>>(
        u_l, u_r, v_l, v_r, pos_u, pos_vl, pos_vr, neg_vl, neg_vr, out);
}